// Round 6
// baseline (105.755 us; speedup 1.0000x reference)
//
#include <hip/hip_runtime.h>
#include <hip/hip_bf16.h>

#define VOCAB 100000
#define EMBED 64
#define NPAIR (1024 * 50)   // B*S
#define KIDS  20

typedef int   int4v   __attribute__((ext_vector_type(4)));
typedef float float2v __attribute__((ext_vector_type(2)));

static __device__ inline ushort f2bf(float f) {
    __hip_bfloat16 h = __float2bfloat16(f);   // RN conversion
    return __builtin_bit_cast(ushort, h);
}
static __device__ inline float bf2f(ushort u) {
    unsigned int v = ((unsigned int)u) << 16;  // exact widening
    return __builtin_bit_cast(float, v);
}

// ---------------------------------------------------------------------------
// Kernel 1: transpose+convert W [E=64, V] fp32 -> Wt [V, E=64] bf16 (12.8 MB).
// W is read once -> nontemporal (don't evict the table from L2).
// Wt writes stay cached (gather will read them).
// ---------------------------------------------------------------------------
__global__ __launch_bounds__(256) void convert_w(const float* __restrict__ W,
                                                 ushort* __restrict__ Wt) {
    __shared__ float tile[64][65];   // +1 pad
    const int v0 = blockIdx.x * 64;
    const int tx = threadIdx.x & 63;   // v offset within tile
    const int ty = threadIdx.x >> 6;   // 0..3
    const int v = v0 + tx;
    if (v < VOCAB) {
        #pragma unroll
        for (int e = ty; e < 64; e += 4) {
            tile[tx][e] = __builtin_nontemporal_load(&W[(size_t)e * VOCAB + v]);
        }
    }
    __syncthreads();
    // Each thread packs 16 bf16 (32 B) of one Wt row.
    const int r  = threadIdx.x >> 2;          // v offset within tile
    const int c0 = (threadIdx.x & 3) * 16;    // e base
    if (v0 + r < VOCAB) {
        uint pk[8];
        #pragma unroll
        for (int i = 0; i < 8; i++) {
            ushort lo = f2bf(tile[r][c0 + 2 * i + 0]);
            ushort hi = f2bf(tile[r][c0 + 2 * i + 1]);
            pk[i] = (uint)lo | ((uint)hi << 16);
        }
        uint4* outv = (uint4*)(Wt + (size_t)(v0 + r) * 64 + c0);
        outv[0] = make_uint4(pk[0], pk[1], pk[2], pk[3]);
        outv[1] = make_uint4(pk[4], pk[5], pk[6], pk[7]);
    }
}

// ---------------------------------------------------------------------------
// Kernel 2: gather-reduce on bf16 table. One wave per (b,s) pair.
// Dword loads, TWO rows per instruction: lanes 0-31 = row 2j, lanes 32-63 =
// row 2j+1; each lane's dword = one bf16 pair (e=2*ll, 2*ll+1). 10 VMEM loads
// instead of 20; half-wave partials combined with one shfl_xor(32).
// ids are stream-once -> nontemporal; out store nontemporal.
// ---------------------------------------------------------------------------
__global__ __launch_bounds__(256) void gather_bf16(const int* __restrict__ ids,
                                                   const uint* __restrict__ Wt32,
                                                   const float* __restrict__ bias,
                                                   float* __restrict__ out) {
    const int wave = (blockIdx.x * blockDim.x + threadIdx.x) >> 6;
    const int lane = threadIdx.x & 63;
    if (wave >= NPAIR) return;

    const int h  = lane >> 5;   // which row of each instruction-pair
    const int ll = lane & 31;   // dword index within the 128B row

    // 20 ids = 5 x int4, 16B-aligned (wave*80 bytes). Stream-once.
    const int4v* idv = (const int4v*)(ids + (size_t)wave * KIDS);
    int4v q0 = __builtin_nontemporal_load(&idv[0]);
    int4v q1 = __builtin_nontemporal_load(&idv[1]);
    int4v q2 = __builtin_nontemporal_load(&idv[2]);
    int4v q3 = __builtin_nontemporal_load(&idv[3]);
    int4v q4 = __builtin_nontemporal_load(&idv[4]);

    // Row pairs for the 10 load instructions.
    uint u0 = Wt32[(((uint)(h ? q0.y : q0.x)) << 5) + ll];
    uint u1 = Wt32[(((uint)(h ? q0.w : q0.z)) << 5) + ll];
    uint u2 = Wt32[(((uint)(h ? q1.y : q1.x)) << 5) + ll];
    uint u3 = Wt32[(((uint)(h ? q1.w : q1.z)) << 5) + ll];
    uint u4 = Wt32[(((uint)(h ? q2.y : q2.x)) << 5) + ll];
    uint u5 = Wt32[(((uint)(h ? q2.w : q2.z)) << 5) + ll];
    uint u6 = Wt32[(((uint)(h ? q3.y : q3.x)) << 5) + ll];
    uint u7 = Wt32[(((uint)(h ? q3.w : q3.z)) << 5) + ll];
    uint u8 = Wt32[(((uint)(h ? q4.y : q4.x)) << 5) + ll];
    uint u9 = Wt32[(((uint)(h ? q4.w : q4.z)) << 5) + ll];

    float accE = 0.f, accO = 0.f;   // even / odd embed dims for this half
    accE += bf2f((ushort)(u0 & 0xffff)); accO += bf2f((ushort)(u0 >> 16));
    accE += bf2f((ushort)(u1 & 0xffff)); accO += bf2f((ushort)(u1 >> 16));
    accE += bf2f((ushort)(u2 & 0xffff)); accO += bf2f((ushort)(u2 >> 16));
    accE += bf2f((ushort)(u3 & 0xffff)); accO += bf2f((ushort)(u3 >> 16));
    accE += bf2f((ushort)(u4 & 0xffff)); accO += bf2f((ushort)(u4 >> 16));
    accE += bf2f((ushort)(u5 & 0xffff)); accO += bf2f((ushort)(u5 >> 16));
    accE += bf2f((ushort)(u6 & 0xffff)); accO += bf2f((ushort)(u6 >> 16));
    accE += bf2f((ushort)(u7 & 0xffff)); accO += bf2f((ushort)(u7 >> 16));
    accE += bf2f((ushort)(u8 & 0xffff)); accO += bf2f((ushort)(u8 >> 16));
    accE += bf2f((ushort)(u9 & 0xffff)); accO += bf2f((ushort)(u9 >> 16));

    // Combine the two half-wave partials (rows of the other parity).
    accE += __shfl_xor(accE, 32);
    accO += __shfl_xor(accO, 32);

    // Add bias and store. Lanes 0-31 write float2 each -> one 256B segment.
    if (h == 0) {
        float2v bb = ((const float2v*)bias)[ll];
        float2v r;
        r.x = accE + bb.x;
        r.y = accO + bb.y;
        __builtin_nontemporal_store(r, &((float2v*)out)[(size_t)wave * 32 + ll]);
    }
}

// ---------------------------------------------------------------------------
// Fallback (ws too small): direct uncoalesced gather on native W [E, V].
// ---------------------------------------------------------------------------
__global__ __launch_bounds__(256) void gather_direct(const int* __restrict__ ids,
                                                     const float* __restrict__ W,
                                                     const float* __restrict__ bias,
                                                     float* __restrict__ out) {
    const int wave = (blockIdx.x * blockDim.x + threadIdx.x) >> 6;
    const int lane = threadIdx.x & 63;
    if (wave >= NPAIR) return;

    const int* myids = ids + (size_t)wave * KIDS;
    float acc = bias[lane];
    #pragma unroll
    for (int k = 0; k < KIDS; k++) {
        int id = myids[k];
        acc += W[(size_t)lane * VOCAB + id];
    }
    out[(size_t)wave * 64 + lane] = acc;
}

extern "C" void kernel_launch(void* const* d_in, const int* in_sizes, int n_in,
                              void* d_out, int out_size, void* d_ws, size_t ws_size,
                              hipStream_t stream) {
    const int*   ids  = (const int*)d_in[0];    // [B,S,K] int32
    const float* W    = (const float*)d_in[1];  // [E, V] fp32
    const float* bias = (const float*)d_in[2];  // [E] fp32
    float*       out  = (float*)d_out;          // [B,S,E] fp32

    const size_t wt_bytes = (size_t)VOCAB * EMBED * sizeof(ushort);  // 12.8 MB

    if (ws_size >= wt_bytes) {
        ushort* Wt = (ushort*)d_ws;
        const int tr_blocks = (VOCAB + 63) / 64;           // 1563
        convert_w<<<tr_blocks, 256, 0, stream>>>(W, Wt);
        const int g_blocks = (NPAIR * 64 + 255) / 256;     // 12800
        gather_bf16<<<g_blocks, 256, 0, stream>>>(ids, (const uint*)Wt, bias, out);
    } else {
        const int g_blocks = (NPAIR * 64 + 255) / 256;
        gather_direct<<<g_blocks, 256, 0, stream>>>(ids, W, bias, out);
    }
}

// Round 7
// 103.394 us; speedup vs baseline: 1.0228x; 1.0228x over previous
//
#include <hip/hip_runtime.h>
#include <hip/hip_bf16.h>

#define VOCAB 100000
#define EMBED 64
#define NPAIR (1024 * 50)   // B*S (even)
#define KIDS  20

typedef int   int4v   __attribute__((ext_vector_type(4)));
typedef float float2v __attribute__((ext_vector_type(2)));

static __device__ inline ushort f2bf(float f) {
    __hip_bfloat16 h = __float2bfloat16(f);   // RN conversion
    return __builtin_bit_cast(ushort, h);
}
static __device__ inline float bf2f(ushort u) {
    unsigned int v = ((unsigned int)u) << 16;  // exact widening
    return __builtin_bit_cast(float, v);
}

// ---------------------------------------------------------------------------
// Kernel 1: transpose+convert W [E=64, V] fp32 -> Wt [V, E=64] bf16 (12.8 MB).
// W is read once -> nontemporal. Wt writes stay cached (gather reads them).
// ---------------------------------------------------------------------------
__global__ __launch_bounds__(256) void convert_w(const float* __restrict__ W,
                                                 ushort* __restrict__ Wt) {
    __shared__ float tile[64][65];   // +1 pad
    const int v0 = blockIdx.x * 64;
    const int tx = threadIdx.x & 63;   // v offset within tile
    const int ty = threadIdx.x >> 6;   // 0..3
    const int v = v0 + tx;
    if (v < VOCAB) {
        #pragma unroll
        for (int e = ty; e < 64; e += 4) {
            tile[tx][e] = __builtin_nontemporal_load(&W[(size_t)e * VOCAB + v]);
        }
    }
    __syncthreads();
    const int r  = threadIdx.x >> 2;          // v offset within tile
    const int c0 = (threadIdx.x & 3) * 16;    // e base
    if (v0 + r < VOCAB) {
        uint pk[8];
        #pragma unroll
        for (int i = 0; i < 8; i++) {
            ushort lo = f2bf(tile[r][c0 + 2 * i + 0]);
            ushort hi = f2bf(tile[r][c0 + 2 * i + 1]);
            pk[i] = (uint)lo | ((uint)hi << 16);
        }
        uint4* outv = (uint4*)(Wt + (size_t)(v0 + r) * 64 + c0);
        outv[0] = make_uint4(pk[0], pk[1], pk[2], pk[3]);
        outv[1] = make_uint4(pk[4], pk[5], pk[6], pk[7]);
    }
}

// ---------------------------------------------------------------------------
// Kernel 2: gather-reduce, TWO pairs per wave (half-wave split, no cndmask).
// Lanes 0-31 = pair 2*pp, lanes 32-63 = pair 2*pp+1. Each half loads its own
// 20 ids (address divergence only), then 20 dword row loads: lane ll covers
// embed dims {2ll, 2ll+1} of its half's row. Independent accumulation per
// half; contiguous 512B nt store per wave. Line count identical to R3;
// instructions per pair halved; dep graph as clean as R3.
// ---------------------------------------------------------------------------
__global__ __launch_bounds__(256) void gather_bf16(const int* __restrict__ ids,
                                                   const uint* __restrict__ Wt32,
                                                   const float* __restrict__ bias,
                                                   float* __restrict__ out) {
    const int pp   = (blockIdx.x * blockDim.x + threadIdx.x) >> 6;  // pair-pair
    const int lane = threadIdx.x & 63;
    if (pp >= NPAIR / 2) return;

    const int h    = lane >> 5;          // which pair of the two
    const int ll   = lane & 31;          // dword index within 128B row
    const int pair = pp * 2 + h;

    // This half's 20 ids: 5 x int4, contiguous, 16B-aligned (pair*80 bytes).
    const int4v* idv = (const int4v*)(ids + (size_t)pair * KIDS);

    float accE = 0.f, accO = 0.f;        // even/odd embed dims for this pair
    #pragma unroll
    for (int k = 0; k < 5; k++) {
        int4v q = idv[k];
        uint u0 = Wt32[(((uint)q.x) << 5) + ll];
        uint u1 = Wt32[(((uint)q.y) << 5) + ll];
        uint u2 = Wt32[(((uint)q.z) << 5) + ll];
        uint u3 = Wt32[(((uint)q.w) << 5) + ll];
        accE += bf2f((ushort)(u0 & 0xffff)); accO += bf2f((ushort)(u0 >> 16));
        accE += bf2f((ushort)(u1 & 0xffff)); accO += bf2f((ushort)(u1 >> 16));
        accE += bf2f((ushort)(u2 & 0xffff)); accO += bf2f((ushort)(u2 >> 16));
        accE += bf2f((ushort)(u3 & 0xffff)); accO += bf2f((ushort)(u3 >> 16));
    }

    float2v bb = ((const float2v*)bias)[ll];
    float2v r;
    r.x = accE + bb.x;                   // dim 2*ll
    r.y = accO + bb.y;                   // dim 2*ll+1
    // Wave writes 2 adjacent pairs' outputs = 512B contiguous.
    __builtin_nontemporal_store(r, &((float2v*)out)[(size_t)pair * 32 + ll]);
}

// ---------------------------------------------------------------------------
// Fallback (ws too small): direct uncoalesced gather on native W [E, V].
// ---------------------------------------------------------------------------
__global__ __launch_bounds__(256) void gather_direct(const int* __restrict__ ids,
                                                     const float* __restrict__ W,
                                                     const float* __restrict__ bias,
                                                     float* __restrict__ out) {
    const int wave = (blockIdx.x * blockDim.x + threadIdx.x) >> 6;
    const int lane = threadIdx.x & 63;
    if (wave >= NPAIR) return;

    const int* myids = ids + (size_t)wave * KIDS;
    float acc = bias[lane];
    #pragma unroll
    for (int k = 0; k < KIDS; k++) {
        int id = myids[k];
        acc += W[(size_t)lane * VOCAB + id];
    }
    out[(size_t)wave * 64 + lane] = acc;
}

extern "C" void kernel_launch(void* const* d_in, const int* in_sizes, int n_in,
                              void* d_out, int out_size, void* d_ws, size_t ws_size,
                              hipStream_t stream) {
    const int*   ids  = (const int*)d_in[0];    // [B,S,K] int32
    const float* W    = (const float*)d_in[1];  // [E, V] fp32
    const float* bias = (const float*)d_in[2];  // [E] fp32
    float*       out  = (float*)d_out;          // [B,S,E] fp32

    const size_t wt_bytes = (size_t)VOCAB * EMBED * sizeof(ushort);  // 12.8 MB

    if (ws_size >= wt_bytes) {
        ushort* Wt = (ushort*)d_ws;
        const int tr_blocks = (VOCAB + 63) / 64;               // 1563
        convert_w<<<tr_blocks, 256, 0, stream>>>(W, Wt);
        const int g_blocks = ((NPAIR / 2) * 64 + 255) / 256;   // 6400
        gather_bf16<<<g_blocks, 256, 0, stream>>>(ids, (const uint*)Wt, bias, out);
    } else {
        const int g_blocks = (NPAIR * 64 + 255) / 256;
        gather_direct<<<g_blocks, 256, 0, stream>>>(ids, W, bias, out);
    }
}